// Round 1
// 1082.438 us; speedup vs baseline: 1.1929x; 1.1929x over previous
//
#include <hip/hip_runtime.h>

// Problem constants
#define B_      4
#define N_      2048
#define KN      30      // neighbors
#define H_      8       // heads
#define D_      64      // head dim
#define CH      512     // NUM_HIDDEN
#define CI      640     // NUM_IN
#define CL      128     // NUM_LATENT
#define BN_TOT  8192    // B_*N_

typedef unsigned short u16;
typedef unsigned int   u32;

typedef __attribute__((ext_vector_type(8))) short bf16x8;
typedef __attribute__((ext_vector_type(4))) float f32x4;

__device__ __forceinline__ float bf2f(u16 u) {
    return __uint_as_float(((u32)u) << 16);
}
__device__ __forceinline__ u16 f2bf(float f) {   // round-to-nearest-even
    u32 u = __float_as_uint(f);
    return (u16)((u + 0x7FFFu + ((u >> 16) & 1u)) >> 16);
}

#define NEG_INF (-3.4028234663852886e38f)

// async global->LDS, 16B per lane; LDS dest = wave-uniform base + lane*16
__device__ __forceinline__ void async16(const void* g, void* l) {
    __builtin_amdgcn_global_load_lds(
        (const __attribute__((address_space(1))) unsigned int*)g,
        (__attribute__((address_space(3))) unsigned int*)l, 16, 0, 0);
}

// ---------------------------------------------------------------------------
// f32 -> bf16 elementwise (n % 4 == 0)
// ---------------------------------------------------------------------------
__global__ __launch_bounds__(256) void cvt_kernel(
    const float* __restrict__ in, u16* __restrict__ out, int n)
{
    int i4 = (blockIdx.x * 256 + threadIdx.x) * 4;
    if (i4 < n) {
        float4 v = *(const float4*)&in[i4];
        ushort4 s;
        s.x = f2bf(v.x); s.y = f2bf(v.y); s.z = f2bf(v.z); s.w = f2bf(v.w);
        *(ushort4*)&out[i4] = s;
    }
}

// ---------------------------------------------------------------------------
// f32 (R x C) -> bf16 transposed (C x R): out[j*R + i] = in[i*C + j]
// ---------------------------------------------------------------------------
__global__ __launch_bounds__(256) void cvt_t_kernel(
    const float* __restrict__ in, u16* __restrict__ out, int R, int Cc)
{
    int o = blockIdx.x * 256 + threadIdx.x;
    if (o < R * Cc) {
        int j = o / R, i = o - j * R;
        out[o] = f2bf(in[(size_t)i * Cc + j]);
    }
}

// ---------------------------------------------------------------------------
// MFMA bf16 GEMM: C[128 x BN] += A[128 x K] * Bt[BN x K]^T  per z-slice.
// A row-major (lda), Bt row-major (ldb) = B^T, C row-major (ldc).
// 256 threads = 4 waves in 2x2 grid; wave tile 64 x (BN/2); 16x16x32 MFMA.
// Staging via global_load_lds width 16 (m97 structure).
// WBIAS: after scaling, add wb[(col-33)*H_ + z] for col>=33 (folds the
// neighbor-attention edge-bias W_b into Qt so attn skips that dot product).
// ---------------------------------------------------------------------------
template<int BN, bool BF16OUT, bool WBIAS>
__global__ __launch_bounds__(256) void mfma_gemm(
    const u16* __restrict__ A, const u16* __restrict__ Bt, void* __restrict__ Cp,
    int K, int lda, int ldb, int ldc,
    long aHead, long bHead, long cHead, float alpha,
    const float* __restrict__ wb)
{
    constexpr int WN = BN / 2;        // wave n-extent
    constexpr int NT = WN / 16;       // n-tiles per wave
    constexpr int BR = (BN * 4) / 256; // B staging rounds

    __shared__ u16 lA[128 * 32];
    __shared__ u16 lB[BN * 32];

    const int t    = threadIdx.x;
    const int w    = t >> 6;
    const int lane = t & 63;
    const int fr   = lane & 15;       // fragment row (m or n)
    const int fq   = lane >> 4;       // quad (k-chunk / acc row group)
    const int wm   = w >> 1, wn = w & 1;
    const int m0   = blockIdx.y * 128;
    const int n0   = blockIdx.x * BN;

    const u16* Ah = A  + (size_t)blockIdx.z * aHead;
    const u16* Bh = Bt + (size_t)blockIdx.z * bHead;

    f32x4 zero = {0.f, 0.f, 0.f, 0.f};
    f32x4 acc[4][NT];
#pragma unroll
    for (int i = 0; i < 4; i++)
#pragma unroll
        for (int j = 0; j < NT; j++) acc[i][j] = zero;

    for (int k0 = 0; k0 < K; k0 += 32) {
        // stage A tile 128x32 (2 rounds of 256 lanes x 16B)
#pragma unroll
        for (int r = 0; r < 2; r++) {
            int chunk = r * 256 + t;
            async16(Ah + (size_t)(m0 + (chunk >> 2)) * lda + k0 + ((chunk & 3) << 3),
                    &lA[(r * 256 + w * 64) * 8]);
        }
        // stage B tile BNx32
#pragma unroll
        for (int r = 0; r < BR; r++) {
            int chunk = r * 256 + t;
            async16(Bh + (size_t)(n0 + (chunk >> 2)) * ldb + k0 + ((chunk & 3) << 3),
                    &lB[(r * 256 + w * 64) * 8]);
        }
        __syncthreads();   // drains vmcnt before barrier

        bf16x8 af[4], bfr[NT];
#pragma unroll
        for (int i = 0; i < 4; i++)
            af[i] = *(const bf16x8*)&lA[(wm * 64 + i * 16 + fr) * 32 + fq * 8];
#pragma unroll
        for (int j = 0; j < NT; j++)
            bfr[j] = *(const bf16x8*)&lB[(wn * WN + j * 16 + fr) * 32 + fq * 8];
#pragma unroll
        for (int i = 0; i < 4; i++)
#pragma unroll
            for (int j = 0; j < NT; j++)
                acc[i][j] = __builtin_amdgcn_mfma_f32_16x16x32_bf16(
                    af[i], bfr[j], acc[i][j], 0, 0, 0);
        __syncthreads();
    }

    // epilogue: C/D layout col=lane&15, row=(lane>>4)*4+reg
    const size_t cbase = (size_t)blockIdx.z * cHead;
#pragma unroll
    for (int i = 0; i < 4; i++) {
        int row = m0 + wm * 64 + i * 16 + fq * 4;
#pragma unroll
        for (int j = 0; j < NT; j++) {
            int col = n0 + wn * WN + j * 16 + fr;
#pragma unroll
            for (int r = 0; r < 4; r++) {
                float v = acc[i][j][r] * alpha;
                if (WBIAS) {
                    if (col >= 33) v += wb[(size_t)(col - 33) * H_ + blockIdx.z];
                }
                if (BF16OUT)
                    ((u16*)Cp)[cbase + (size_t)(row + r) * ldc + col] = f2bf(v);
                else
                    ((float*)Cp)[cbase + (size_t)(row + r) * ldc + col] = v;
            }
        }
    }
}

// ---------------------------------------------------------------------------
// biasL[b][k*8+h] = (z @ W_z)[b, k*8+h]
// ---------------------------------------------------------------------------
__global__ __launch_bounds__(256) void biasl_kernel(
    const float* __restrict__ z, const float* __restrict__ Wz,
    float* __restrict__ biasL)
{
    const int t = threadIdx.x;
    if (t < KN * H_) {
        for (int b = 0; b < B_; b++) {
            float s = 0.f;
            for (int l = 0; l < CL; l++) s += z[b * CL + l] * Wz[l * (KN * H_) + t];
            biasL[b * (KN * H_) + t] = s;
        }
    }
}

// ---------------------------------------------------------------------------
// Fused attention: one block per (b,n). h_E tile staged once in LDS (bf16),
// rows XOR-swizzled (byte ^= (k&7)<<4; row stride 1280B = 10*128B so the
// swizzle is row-local and bijective).
// Phase 1 (waves 0,1): logits[8x30] = Qt'[8x640] . ehs[30x640]^T via
//   mfma_f32_16x16x32_bf16 (A-frags straight from global Qt; bias_edges is
//   already folded into Qt by gemm2's WBIAS epilogue). + biasL + mask.
// Phase 2: softmax over k per head (8 threads).
// Phase 3: E_agg[h][c] = sum_k attend*hE (160 threads, scalar, bf16 out).
// NOTE: Qt and Eagg alias (in-place); reads/writes to the same bn-slice are
// separated by __syncthreads. No __restrict__ on those params.
// ---------------------------------------------------------------------------
#define LGS 33   // logit_s row stride (pad 32->33)

__global__ __launch_bounds__(256) void attn_kernel(
    const float* __restrict__ hE, const float* __restrict__ mask,
    const u16* Qt, const float* __restrict__ biasL, u16* Eagg)
{
    __shared__ __align__(16) u16 ehs[KN * CI];   // 38400 B, swizzled rows
    __shared__ float logit_s[H_ * LGS];          // [h][k]  1056 B
    __shared__ float att_s[KN * H_];             // [k][h]   960 B
    __shared__ float mask_s[KN];                 //          120 B
    // total 40536 B  -> still 4 blocks/CU

    const int bn   = blockIdx.x;
    const int b    = bn >> 11;              // N_=2048
    const int t    = threadIdx.x;
    const int w    = t >> 6;
    const int lane = t & 63;
    const int fr   = lane & 15;
    const int fq   = lane >> 4;
    char* ebase = (char*)ehs;

    // ---- stage h_E[b,n] -> LDS bf16 (swizzled) ----
    const float* he = hE + (size_t)bn * KN * CI;
    for (int idx = t; idx < KN * CI / 4; idx += 256) {   // 4800 float4 groups
        int k = idx / 160;
        int c = (idx - k * 160) << 2;
        float4 v = *(const float4*)&he[k * CI + c];
        ushort4 sv;
        sv.x = f2bf(v.x); sv.y = f2bf(v.y); sv.z = f2bf(v.z); sv.w = f2bf(v.w);
        *(ushort4*)(ebase + ((k * 1280 + (c << 1)) ^ ((k & 7) << 4))) = sv;
    }
    if (t < KN) mask_s[t] = mask[(size_t)bn * KN + t];
    __syncthreads();

    // ---- logits via MFMA: wave j in {0,1} computes neighbor tile j ----
    if (w < 2) {
        // A fragment: row = head (fr&7 duplicates rows 8-15 -> discarded C rows)
        const u16* qrow = Qt + (size_t)bn * (H_ * CI) + (fr & 7) * CI + fq * 8;
        int nr = w * 16 + fr;                 // neighbor row for B fragment
        if (nr > KN - 1) nr = KN - 1;         // clamp pad rows 30,31 (discarded)
        const char* erow = ebase + nr * 1280;
        const int swz = (nr & 7) << 4;
        f32x4 lacc = {0.f, 0.f, 0.f, 0.f};
#pragma unroll 4
        for (int kk = 0; kk < CI / 32; kk++) {           // 20 k-steps
            bf16x8 a  = *(const bf16x8*)(qrow + kk * 32);
            bf16x8 bf = *(const bf16x8*)(erow + ((kk * 64 + fq * 16) ^ swz));
            lacc = __builtin_amdgcn_mfma_f32_16x16x32_bf16(a, bf, lacc, 0, 0, 0);
        }
        // C layout: col = fr (neighbor within tile), row = fq*4+r (head 0-7)
        int k = w * 16 + fr;
        if (fq < 2 && k < KN) {
            float mk = mask_s[k];
            const float* blp = &biasL[b * (KN * H_) + k * H_];
#pragma unroll
            for (int r = 0; r < 4; r++) {
                int h = fq * 4 + r;
                float lg = lacc[r] + blp[h];
                logit_s[h * LGS + k] = (mk > 0.f) ? lg : NEG_INF;
            }
        }
    }
    __syncthreads();

    // ---- softmax over k, per head ----
    if (t < H_) {
        const int h = t;
        float m = NEG_INF;
#pragma unroll
        for (int k = 0; k < KN; k++) m = fmaxf(m, logit_s[h * LGS + k]);
        float e[KN];
        float s = 0.f;
#pragma unroll
        for (int k = 0; k < KN; k++) { e[k] = __expf(logit_s[h * LGS + k] - m); s += e[k]; }
        float inv = 1.f / s;
#pragma unroll
        for (int k = 0; k < KN; k++) att_s[k * H_ + h] = e[k] * inv * mask_s[k];
    }
    __syncthreads();

    // ---- E_agg[h][c] = sum_k attend[h][k] * hE[k][c] ----
    if (t < 160) {
        const int c0 = t << 2;
        float acc[8][4] = {};
        for (int k = 0; k < KN; k++) {
            ushort4 ev = *(const ushort4*)(ebase + ((k * 1280 + (c0 << 1)) ^ ((k & 7) << 4)));
            float f0 = bf2f(ev.x), f1 = bf2f(ev.y), f2 = bf2f(ev.z), f3 = bf2f(ev.w);
            float4 a0 = *(const float4*)&att_s[k * H_];
            float4 a1 = *(const float4*)&att_s[k * H_ + 4];
            float aw[8] = {a0.x, a0.y, a0.z, a0.w, a1.x, a1.y, a1.z, a1.w};
#pragma unroll
            for (int h = 0; h < 8; h++) {
                acc[h][0] += aw[h] * f0; acc[h][1] += aw[h] * f1;
                acc[h][2] += aw[h] * f2; acc[h][3] += aw[h] * f3;
            }
        }
#pragma unroll
        for (int h = 0; h < 8; h++) {
            ushort4 sv;
            sv.x = f2bf(acc[h][0]); sv.y = f2bf(acc[h][1]);
            sv.z = f2bf(acc[h][2]); sv.w = f2bf(acc[h][3]);
            *(ushort4*)&Eagg[((size_t)bn * H_ + h) * CI + c0] = sv;
        }
    }
}

// ---------------------------------------------------------------------------
extern "C" void kernel_launch(void* const* d_in, const int* in_sizes, int n_in,
                              void* d_out, int out_size, void* d_ws, size_t ws_size,
                              hipStream_t stream)
{
    const float* z    = (const float*)d_in[0];
    const float* hV   = (const float*)d_in[1];
    const float* hE   = (const float*)d_in[2];
    const float* mask = (const float*)d_in[3];
    const float* WQ   = (const float*)d_in[4];
    const float* WK   = (const float*)d_in[5];
    const float* WV   = (const float*)d_in[6];
    const float* WO   = (const float*)d_in[7];
    const float* Wz   = (const float*)d_in[8];
    const float* Wb   = (const float*)d_in[9];
    float* out = (float*)d_out;

    char* w = (char*)d_ws;
    // ws layout (~103 MB):
    //  [0,        8.39 MB)  hV_bf (bf16), reused as Hupd_bf after gemm1
    //  [8.39,    16.78 MB)  Q_bf  (bf16)
    //  [16.78,  100.66 MB)  Qt (bf16) 8192x8x640 — Eagg written IN-PLACE here
    //  [100.66 MB, +2.4 MB) WQt, WK_bf, WVt, WOt (bf16), biasL (f32)
    u16*   hV_bf = (u16*)w;
    u16*   Q_bf  = (u16*)(w + 8388608);
    u16*   Qt    = (u16*)(w + 16777216);
    u16*   WQt   = (u16*)(w + 100663296);
    u16*   WK_bf = (u16*)(w + 101187584);
    u16*   WVt   = (u16*)(w + 101842944);
    u16*   WOt   = (u16*)(w + 102498304);
    float* biasL = (float*)(w + 103022592);
    u16*   Eagg  = Qt;       // in-place
    u16*   Hupd  = hV_bf;    // hV_bf dead after gemm1

    // 0) conversions
    cvt_kernel<<<4096, 256, 0, stream>>>(hV, hV_bf, BN_TOT * CH);
    cvt_kernel<<<320, 256, 0, stream>>>(WK, WK_bf, CI * CH);
    cvt_t_kernel<<<1024, 256, 0, stream>>>(WQ, WQt, CH, CH);      // WQt[n][k]
    cvt_t_kernel<<<1280, 256, 0, stream>>>(WV, WVt, CI, CH);      // WVt[d][c]
    cvt_t_kernel<<<1024, 256, 0, stream>>>(WO, WOt, CH, CH);      // WOt[n][k]
    biasl_kernel<<<1, 256, 0, stream>>>(z, Wz, biasL);

    // 1) Q_bf = hV @ W_Q          (M=8192, N=512, K=512)
    mfma_gemm<128, true, false><<<dim3(4, 64, 1), 256, 0, stream>>>(
        hV_bf, WQt, Q_bf, CH, CH, CH, CH, 0, 0, 0, 1.0f, nullptr);
    // 2) Qt = per-head (Q_h @ W_K_h^T)/8 + Wb-fold   (M=8192, N=640, K=64)
    mfma_gemm<128, true, true><<<dim3(5, 64, H_), 256, 0, stream>>>(
        Q_bf, WK_bf, Qt, 64, CH, CH, H_ * CI, 64, 64, CI, 0.125f, Wb);
    // 3) fused logits/softmax/aggregate (Eagg in-place over Qt)
    attn_kernel<<<dim3(BN_TOT), 256, 0, stream>>>(hE, mask, Qt, biasL, Eagg);
    // 4) Hupd = per-head Eagg_h @ W_V_h      (M=8192, N=64, K=640, z=head)
    mfma_gemm<64, true, false><<<dim3(1, 64, H_), 256, 0, stream>>>(
        Eagg, WVt, Hupd, CI, H_ * CI, CI, CH, CI, 64L * CI, 64, 1.0f, nullptr);
    // 5) out = Hupd @ W_O          (M=8192, N=512, K=512)
    mfma_gemm<128, false, false><<<dim3(4, 64, 1), 256, 0, stream>>>(
        Hupd, WOt, out, CH, CH, CH, CH, 0, 0, 0, 1.0f, nullptr);
}

// Round 2
// 1061.364 us; speedup vs baseline: 1.2166x; 1.0199x over previous
//
#include <hip/hip_runtime.h>

// Problem constants
#define B_      4
#define N_      2048
#define KN      30      // neighbors
#define H_      8       // heads
#define D_      64      // head dim
#define CH      512     // NUM_HIDDEN
#define CI      640     // NUM_IN
#define CL      128     // NUM_LATENT
#define BN_TOT  8192    // B_*N_

typedef unsigned short u16;
typedef unsigned int   u32;

typedef __attribute__((ext_vector_type(8))) short bf16x8;
typedef __attribute__((ext_vector_type(4))) float f32x4;

__device__ __forceinline__ float bf2f(u16 u) {
    return __uint_as_float(((u32)u) << 16);
}
__device__ __forceinline__ u16 f2bf(float f) {   // round-to-nearest-even
    u32 u = __float_as_uint(f);
    return (u16)((u + 0x7FFFu + ((u >> 16) & 1u)) >> 16);
}

#define NEG_INF (-3.4028234663852886e38f)

// async global->LDS, 16B per lane; LDS dest = wave-uniform base + lane*16
__device__ __forceinline__ void async16(const void* g, void* l) {
    __builtin_amdgcn_global_load_lds(
        (const __attribute__((address_space(1))) unsigned int*)g,
        (__attribute__((address_space(3))) unsigned int*)l, 16, 0, 0);
}

// ---------------------------------------------------------------------------
// f32 -> bf16 elementwise (n % 4 == 0)
// ---------------------------------------------------------------------------
__global__ __launch_bounds__(256) void cvt_kernel(
    const float* __restrict__ in, u16* __restrict__ out, int n)
{
    int i4 = (blockIdx.x * 256 + threadIdx.x) * 4;
    if (i4 < n) {
        float4 v = *(const float4*)&in[i4];
        ushort4 s;
        s.x = f2bf(v.x); s.y = f2bf(v.y); s.z = f2bf(v.z); s.w = f2bf(v.w);
        *(ushort4*)&out[i4] = s;
    }
}

// ---------------------------------------------------------------------------
// f32 (R x C) -> bf16 transposed (C x R): out[j*R + i] = in[i*C + j]
// ---------------------------------------------------------------------------
__global__ __launch_bounds__(256) void cvt_t_kernel(
    const float* __restrict__ in, u16* __restrict__ out, int R, int Cc)
{
    int o = blockIdx.x * 256 + threadIdx.x;
    if (o < R * Cc) {
        int j = o / R, i = o - j * R;
        out[o] = f2bf(in[(size_t)i * Cc + j]);
    }
}

// ---------------------------------------------------------------------------
// MFMA bf16 GEMM: C[128 x BN] += A[128 x K] * Bt[BN x K]^T  per z-slice.
// A row-major (lda), Bt row-major (ldb) = B^T, C row-major (ldc).
// 256 threads = 4 waves in 2x2 grid; wave tile 64 x (BN/2); 16x16x32 MFMA.
// Staging via global_load_lds width 16 (m97 structure).
// WBIAS: after scaling, add wb[(col-33)*H_ + z] for col>=33 (folds the
// neighbor-attention edge-bias W_b into Qt so attn skips that dot product).
// ---------------------------------------------------------------------------
template<int BN, bool BF16OUT, bool WBIAS>
__global__ __launch_bounds__(256) void mfma_gemm(
    const u16* __restrict__ A, const u16* __restrict__ Bt, void* __restrict__ Cp,
    int K, int lda, int ldb, int ldc,
    long aHead, long bHead, long cHead, float alpha,
    const float* __restrict__ wb)
{
    constexpr int WN = BN / 2;        // wave n-extent
    constexpr int NT = WN / 16;       // n-tiles per wave
    constexpr int BR = (BN * 4) / 256; // B staging rounds

    __shared__ u16 lA[128 * 32];
    __shared__ u16 lB[BN * 32];

    const int t    = threadIdx.x;
    const int w    = t >> 6;
    const int lane = t & 63;
    const int fr   = lane & 15;       // fragment row (m or n)
    const int fq   = lane >> 4;       // quad (k-chunk / acc row group)
    const int wm   = w >> 1, wn = w & 1;
    const int m0   = blockIdx.y * 128;
    const int n0   = blockIdx.x * BN;

    const u16* Ah = A  + (size_t)blockIdx.z * aHead;
    const u16* Bh = Bt + (size_t)blockIdx.z * bHead;

    f32x4 zero = {0.f, 0.f, 0.f, 0.f};
    f32x4 acc[4][NT];
#pragma unroll
    for (int i = 0; i < 4; i++)
#pragma unroll
        for (int j = 0; j < NT; j++) acc[i][j] = zero;

    for (int k0 = 0; k0 < K; k0 += 32) {
        // stage A tile 128x32 (2 rounds of 256 lanes x 16B)
#pragma unroll
        for (int r = 0; r < 2; r++) {
            int chunk = r * 256 + t;
            async16(Ah + (size_t)(m0 + (chunk >> 2)) * lda + k0 + ((chunk & 3) << 3),
                    &lA[(r * 256 + w * 64) * 8]);
        }
        // stage B tile BNx32
#pragma unroll
        for (int r = 0; r < BR; r++) {
            int chunk = r * 256 + t;
            async16(Bh + (size_t)(n0 + (chunk >> 2)) * ldb + k0 + ((chunk & 3) << 3),
                    &lB[(r * 256 + w * 64) * 8]);
        }
        __syncthreads();   // drains vmcnt before barrier

        bf16x8 af[4], bfr[NT];
#pragma unroll
        for (int i = 0; i < 4; i++)
            af[i] = *(const bf16x8*)&lA[(wm * 64 + i * 16 + fr) * 32 + fq * 8];
#pragma unroll
        for (int j = 0; j < NT; j++)
            bfr[j] = *(const bf16x8*)&lB[(wn * WN + j * 16 + fr) * 32 + fq * 8];
#pragma unroll
        for (int i = 0; i < 4; i++)
#pragma unroll
            for (int j = 0; j < NT; j++)
                acc[i][j] = __builtin_amdgcn_mfma_f32_16x16x32_bf16(
                    af[i], bfr[j], acc[i][j], 0, 0, 0);
        __syncthreads();
    }

    // epilogue: C/D layout col=lane&15, row=(lane>>4)*4+reg
    const size_t cbase = (size_t)blockIdx.z * cHead;
#pragma unroll
    for (int i = 0; i < 4; i++) {
        int row = m0 + wm * 64 + i * 16 + fq * 4;
#pragma unroll
        for (int j = 0; j < NT; j++) {
            int col = n0 + wn * WN + j * 16 + fr;
#pragma unroll
            for (int r = 0; r < 4; r++) {
                float v = acc[i][j][r] * alpha;
                if (WBIAS) {
                    if (col >= 33) v += wb[(size_t)(col - 33) * H_ + blockIdx.z];
                }
                if (BF16OUT)
                    ((u16*)Cp)[cbase + (size_t)(row + r) * ldc + col] = f2bf(v);
                else
                    ((float*)Cp)[cbase + (size_t)(row + r) * ldc + col] = v;
            }
        }
    }
}

// ---------------------------------------------------------------------------
// biasL[b][k*8+h] = (z @ W_z)[b, k*8+h]
// ---------------------------------------------------------------------------
__global__ __launch_bounds__(256) void biasl_kernel(
    const float* __restrict__ z, const float* __restrict__ Wz,
    float* __restrict__ biasL)
{
    const int t = threadIdx.x;
    if (t < KN * H_) {
        for (int b = 0; b < B_; b++) {
            float s = 0.f;
            for (int l = 0; l < CL; l++) s += z[b * CL + l] * Wz[l * (KN * H_) + t];
            biasL[b * (KN * H_) + t] = s;
        }
    }
}

// ---------------------------------------------------------------------------
// Fused attention: one block per (b,n).
// Staging phase: h_E[b,n] (30x640 f32) -> LDS bf16, XOR-swizzled rows
// (byte ^= (k&7)<<4, row stride 1280B); Qt[b,n] (8x640 bf16) -> LDS with the
// same swizzle (coalesced bf16x8 reads; kills the global-latency exposure the
// previous version had inside the MFMA loop).
// Phase 1 (waves 0,1): logits[8x30] via mfma_f32_16x16x32_bf16, both operands
//   from LDS. + biasL + mask.
// Phase 2: wave-parallel softmax (64 lanes; lane=(h,kgroup); __shfl_xor over
//   8-lane groups).
// Phase 3: E_agg[h][c] = sum_k attend*hE (160 threads, scalar, bf16 out).
// LDS ~50.7 KB -> 3 blocks/CU.
// NOTE: Qt and Eagg alias (in-place); Qt is fully copied to LDS before the
// first barrier; Eagg writes happen after. No __restrict__ on those params.
// ---------------------------------------------------------------------------
__global__ __launch_bounds__(256) void attn_kernel(
    const float* __restrict__ hE, const float* __restrict__ mask,
    const u16* Qt, const float* __restrict__ biasL, u16* Eagg)
{
    __shared__ __align__(16) u16 ehs[KN * CI];   // 38400 B, swizzled rows
    __shared__ __align__(16) u16 lqt[H_ * CI];   // 10240 B, swizzled rows
    __shared__ float logit_s[H_ * 32];           // [h][32]  1024 B
    __shared__ float att_s[KN * H_];             // [k][h]    960 B
    __shared__ float mask_s[KN];                 //           120 B

    const int bn   = blockIdx.x;
    const int b    = bn >> 11;              // N_=2048
    const int t    = threadIdx.x;
    const int w    = t >> 6;
    const int lane = t & 63;
    const int fr   = lane & 15;
    const int fq   = lane >> 4;
    char* ebase = (char*)ehs;
    char* qbase = (char*)lqt;

    // ---- stage h_E[b,n] -> LDS bf16 (swizzled) ----
    const float* he = hE + (size_t)bn * KN * CI;
    {
        int idx = t;
#pragma unroll 6
        for (int it = 0; it < 18; ++it, idx += 256) {   // 18*256 = 4608 groups
            int k = idx / 160;
            int c = (idx - k * 160) << 2;
            float4 v = *(const float4*)&he[k * CI + c];
            ushort4 sv;
            sv.x = f2bf(v.x); sv.y = f2bf(v.y); sv.z = f2bf(v.z); sv.w = f2bf(v.w);
            *(ushort4*)(ebase + ((k * 1280 + (c << 1)) ^ ((k & 7) << 4))) = sv;
        }
        if (t < 192) {                                   // tail: 4608..4799
            int idx2 = 4608 + t;
            int k = idx2 / 160;
            int c = (idx2 - k * 160) << 2;
            float4 v = *(const float4*)&he[k * CI + c];
            ushort4 sv;
            sv.x = f2bf(v.x); sv.y = f2bf(v.y); sv.z = f2bf(v.z); sv.w = f2bf(v.w);
            *(ushort4*)(ebase + ((k * 1280 + (c << 1)) ^ ((k & 7) << 4))) = sv;
        }
    }
    // ---- stage Qt[b,n] (8x640 bf16, contiguous 10240B) -> LDS (swizzled) ----
    {
        const u16* qg = Qt + (size_t)bn * (H_ * CI);
        for (int idx = t; idx < 640; idx += 256) {       // 16B chunks
            int row = idx / 80;                          // head 0..7
            bf16x8 v = *(const bf16x8*)(qg + idx * 8);
            *(bf16x8*)(qbase + ((idx * 16) ^ ((row & 7) << 4))) = v;
        }
    }
    if (t < KN) mask_s[t] = mask[(size_t)bn * KN + t];
    __syncthreads();

    // ---- logits via MFMA: wave j in {0,1} computes neighbor tile j ----
    if (w < 2) {
        const int h8   = fr & 7;              // A row = head (rows 8-15 dup)
        const int qswz = h8 << 4;
        int nr = w * 16 + fr;                 // neighbor row for B fragment
        if (nr > KN - 1) nr = KN - 1;         // clamp pad rows 30,31 (discarded)
        const char* erow = ebase + nr * 1280;
        const int swz = (nr & 7) << 4;
        f32x4 lacc = {0.f, 0.f, 0.f, 0.f};
#pragma unroll 4
        for (int kk = 0; kk < CI / 32; kk++) {           // 20 k-steps
            bf16x8 a  = *(const bf16x8*)(qbase + ((h8 * 1280 + kk * 64 + fq * 16) ^ qswz));
            bf16x8 bf = *(const bf16x8*)(erow + ((kk * 64 + fq * 16) ^ swz));
            lacc = __builtin_amdgcn_mfma_f32_16x16x32_bf16(a, bf, lacc, 0, 0, 0);
        }
        // C layout: col = fr (neighbor within tile), row = fq*4+r (head 0-7)
        int k = w * 16 + fr;
        if (fq < 2 && k < KN) {
            float mk = mask_s[k];
            const float* blp = &biasL[b * (KN * H_) + k * H_];
#pragma unroll
            for (int r = 0; r < 4; r++) {
                int h = fq * 4 + r;
                float lg = lacc[r] + blp[h];
                logit_s[h * 32 + k] = (mk > 0.f) ? lg : NEG_INF;
            }
        }
    }
    __syncthreads();

    // ---- softmax over k, wave-parallel: lane -> (h = t>>3, kg = t&7) ----
    if (t < 64) {
        const int h  = t >> 3;
        const int kg = t & 7;
        float lv[4];
#pragma unroll
        for (int i = 0; i < 4; i++) {
            int k = kg * 4 + i;
            float v = logit_s[h * 32 + k];
            lv[i] = (k < KN) ? v : NEG_INF;   // rows 30,31 are garbage
        }
        float m = fmaxf(fmaxf(lv[0], lv[1]), fmaxf(lv[2], lv[3]));
        m = fmaxf(m, __shfl_xor(m, 1));
        m = fmaxf(m, __shfl_xor(m, 2));
        m = fmaxf(m, __shfl_xor(m, 4));
        float e[4], s = 0.f;
#pragma unroll
        for (int i = 0; i < 4; i++) { e[i] = __expf(lv[i] - m); s += e[i]; }
        s += __shfl_xor(s, 1);
        s += __shfl_xor(s, 2);
        s += __shfl_xor(s, 4);
        float inv = 1.f / s;
#pragma unroll
        for (int i = 0; i < 4; i++) {
            int k = kg * 4 + i;
            if (k < KN) att_s[k * H_ + h] = e[i] * inv * mask_s[k];
        }
    }
    __syncthreads();

    // ---- E_agg[h][c] = sum_k attend[h][k] * hE[k][c] ----
    if (t < 160) {
        const int c0 = t << 2;
        float acc[8][4] = {};
        for (int k = 0; k < KN; k++) {
            ushort4 ev = *(const ushort4*)(ebase + ((k * 1280 + (c0 << 1)) ^ ((k & 7) << 4)));
            float f0 = bf2f(ev.x), f1 = bf2f(ev.y), f2 = bf2f(ev.z), f3 = bf2f(ev.w);
            float4 a0 = *(const float4*)&att_s[k * H_];
            float4 a1 = *(const float4*)&att_s[k * H_ + 4];
            float aw[8] = {a0.x, a0.y, a0.z, a0.w, a1.x, a1.y, a1.z, a1.w};
#pragma unroll
            for (int h = 0; h < 8; h++) {
                acc[h][0] += aw[h] * f0; acc[h][1] += aw[h] * f1;
                acc[h][2] += aw[h] * f2; acc[h][3] += aw[h] * f3;
            }
        }
#pragma unroll
        for (int h = 0; h < 8; h++) {
            ushort4 sv;
            sv.x = f2bf(acc[h][0]); sv.y = f2bf(acc[h][1]);
            sv.z = f2bf(acc[h][2]); sv.w = f2bf(acc[h][3]);
            *(ushort4*)&Eagg[((size_t)bn * H_ + h) * CI + c0] = sv;
        }
    }
}

// ---------------------------------------------------------------------------
extern "C" void kernel_launch(void* const* d_in, const int* in_sizes, int n_in,
                              void* d_out, int out_size, void* d_ws, size_t ws_size,
                              hipStream_t stream)
{
    const float* z    = (const float*)d_in[0];
    const float* hV   = (const float*)d_in[1];
    const float* hE   = (const float*)d_in[2];
    const float* mask = (const float*)d_in[3];
    const float* WQ   = (const float*)d_in[4];
    const float* WK   = (const float*)d_in[5];
    const float* WV   = (const float*)d_in[6];
    const float* WO   = (const float*)d_in[7];
    const float* Wz   = (const float*)d_in[8];
    const float* Wb   = (const float*)d_in[9];
    float* out = (float*)d_out;

    char* w = (char*)d_ws;
    // ws layout (~103 MB):
    //  [0,        8.39 MB)  hV_bf (bf16), reused as Hupd_bf after gemm1
    //  [8.39,    16.78 MB)  Q_bf  (bf16)
    //  [16.78,  100.66 MB)  Qt (bf16) 8192x8x640 — Eagg written IN-PLACE here
    //  [100.66 MB, +2.4 MB) WQt, WK_bf, WVt, WOt (bf16), biasL (f32)
    u16*   hV_bf = (u16*)w;
    u16*   Q_bf  = (u16*)(w + 8388608);
    u16*   Qt    = (u16*)(w + 16777216);
    u16*   WQt   = (u16*)(w + 100663296);
    u16*   WK_bf = (u16*)(w + 101187584);
    u16*   WVt   = (u16*)(w + 101842944);
    u16*   WOt   = (u16*)(w + 102498304);
    float* biasL = (float*)(w + 103022592);
    u16*   Eagg  = Qt;       // in-place
    u16*   Hupd  = hV_bf;    // hV_bf dead after gemm1

    // 0) conversions
    cvt_kernel<<<4096, 256, 0, stream>>>(hV, hV_bf, BN_TOT * CH);
    cvt_kernel<<<320, 256, 0, stream>>>(WK, WK_bf, CI * CH);
    cvt_t_kernel<<<1024, 256, 0, stream>>>(WQ, WQt, CH, CH);      // WQt[n][k]
    cvt_t_kernel<<<1280, 256, 0, stream>>>(WV, WVt, CI, CH);      // WVt[d][c]
    cvt_t_kernel<<<1024, 256, 0, stream>>>(WO, WOt, CH, CH);      // WOt[n][k]
    biasl_kernel<<<1, 256, 0, stream>>>(z, Wz, biasL);

    // 1) Q_bf = hV @ W_Q          (M=8192, N=512, K=512)
    mfma_gemm<128, true, false><<<dim3(4, 64, 1), 256, 0, stream>>>(
        hV_bf, WQt, Q_bf, CH, CH, CH, CH, 0, 0, 0, 1.0f, nullptr);
    // 2) Qt = per-head (Q_h @ W_K_h^T)/8 + Wb-fold   (M=8192, N=640, K=64)
    mfma_gemm<128, true, true><<<dim3(5, 64, H_), 256, 0, stream>>>(
        Q_bf, WK_bf, Qt, 64, CH, CH, H_ * CI, 64, 64, CI, 0.125f, Wb);
    // 3) fused logits/softmax/aggregate (Eagg in-place over Qt)
    attn_kernel<<<dim3(BN_TOT), 256, 0, stream>>>(hE, mask, Qt, biasL, Eagg);
    // 4) Hupd = per-head Eagg_h @ W_V_h      (M=8192, N=64, K=640, z=head)
    mfma_gemm<64, true, false><<<dim3(1, 64, H_), 256, 0, stream>>>(
        Eagg, WVt, Hupd, CI, H_ * CI, CI, CH, CI, 64L * CI, 64, 1.0f, nullptr);
    // 5) out = Hupd @ W_O          (M=8192, N=512, K=512)
    mfma_gemm<128, false, false><<<dim3(4, 64, 1), 256, 0, stream>>>(
        Hupd, WOt, out, CH, CH, CH, CH, 0, 0, 0, 1.0f, nullptr);
}

// Round 4
// 1051.560 us; speedup vs baseline: 1.2279x; 1.0093x over previous
//
#include <hip/hip_runtime.h>

// Problem constants
#define B_      4
#define N_      2048
#define KN      30      // neighbors
#define H_      8       // heads
#define D_      64      // head dim
#define CH      512     // NUM_HIDDEN
#define CI      640     // NUM_IN
#define CL      128     // NUM_LATENT
#define BN_TOT  8192    // B_*N_

typedef unsigned short u16;
typedef unsigned int   u32;

typedef __attribute__((ext_vector_type(8))) short bf16x8;
typedef __attribute__((ext_vector_type(4))) float f32x4;

__device__ __forceinline__ float bf2f(u16 u) {
    return __uint_as_float(((u32)u) << 16);
}
__device__ __forceinline__ u16 f2bf(float f) {   // round-to-nearest-even
    u32 u = __float_as_uint(f);
    return (u16)((u + 0x7FFFu + ((u >> 16) & 1u)) >> 16);
}
// HW packed f32->bf16 (RNE), 1 instr for 2 elements (no builtin on gfx950)
__device__ __forceinline__ u32 pk2bf(float lo, float hi) {
    u32 r;
    asm("v_cvt_pk_bf16_f32 %0, %1, %2" : "=v"(r) : "v"(lo), "v"(hi));
    return r;
}
__device__ __forceinline__ u16 f2bf1(float f) {
    return (u16)pk2bf(f, f);
}

#define NEG_INF (-3.4028234663852886e38f)

// async global->LDS, 16B per lane; LDS dest = wave-uniform base + lane*16
__device__ __forceinline__ void async16(const void* g, void* l) {
    __builtin_amdgcn_global_load_lds(
        (const __attribute__((address_space(1))) unsigned int*)g,
        (__attribute__((address_space(3))) unsigned int*)l, 16, 0, 0);
}

// ---------------------------------------------------------------------------
// f32 -> bf16 elementwise (n % 4 == 0)
// ---------------------------------------------------------------------------
__global__ __launch_bounds__(256) void cvt_kernel(
    const float* __restrict__ in, u16* __restrict__ out, int n)
{
    int i4 = (blockIdx.x * 256 + threadIdx.x) * 4;
    if (i4 < n) {
        float4 v = *(const float4*)&in[i4];
        ushort4 s;
        s.x = f2bf(v.x); s.y = f2bf(v.y); s.z = f2bf(v.z); s.w = f2bf(v.w);
        *(ushort4*)&out[i4] = s;
    }
}

// ---------------------------------------------------------------------------
// f32 (R x C) -> bf16 transposed (C x R): out[j*R + i] = in[i*C + j]
// ---------------------------------------------------------------------------
__global__ __launch_bounds__(256) void cvt_t_kernel(
    const float* __restrict__ in, u16* __restrict__ out, int R, int Cc)
{
    int o = blockIdx.x * 256 + threadIdx.x;
    if (o < R * Cc) {
        int j = o / R, i = o - j * R;
        out[o] = f2bf(in[(size_t)i * Cc + j]);
    }
}

// ---------------------------------------------------------------------------
// MFMA bf16 GEMM: C[128 x BN] += A[128 x K] * Bt[BN x K]^T  per z-slice.
// (unchanged m97 structure; see earlier rounds)
// ---------------------------------------------------------------------------
template<int BN, bool BF16OUT, bool WBIAS>
__global__ __launch_bounds__(256) void mfma_gemm(
    const u16* __restrict__ A, const u16* __restrict__ Bt, void* __restrict__ Cp,
    int K, int lda, int ldb, int ldc,
    long aHead, long bHead, long cHead, float alpha,
    const float* __restrict__ wb)
{
    constexpr int WN = BN / 2;        // wave n-extent
    constexpr int NT = WN / 16;       // n-tiles per wave
    constexpr int BR = (BN * 4) / 256; // B staging rounds

    __shared__ u16 lA[128 * 32];
    __shared__ u16 lB[BN * 32];

    const int t    = threadIdx.x;
    const int w    = t >> 6;
    const int lane = t & 63;
    const int fr   = lane & 15;       // fragment row (m or n)
    const int fq   = lane >> 4;       // quad (k-chunk / acc row group)
    const int wm   = w >> 1, wn = w & 1;
    const int m0   = blockIdx.y * 128;
    const int n0   = blockIdx.x * BN;

    const u16* Ah = A  + (size_t)blockIdx.z * aHead;
    const u16* Bh = Bt + (size_t)blockIdx.z * bHead;

    f32x4 zero = {0.f, 0.f, 0.f, 0.f};
    f32x4 acc[4][NT];
#pragma unroll
    for (int i = 0; i < 4; i++)
#pragma unroll
        for (int j = 0; j < NT; j++) acc[i][j] = zero;

    for (int k0 = 0; k0 < K; k0 += 32) {
        // stage A tile 128x32 (2 rounds of 256 lanes x 16B)
#pragma unroll
        for (int r = 0; r < 2; r++) {
            int chunk = r * 256 + t;
            async16(Ah + (size_t)(m0 + (chunk >> 2)) * lda + k0 + ((chunk & 3) << 3),
                    &lA[(r * 256 + w * 64) * 8]);
        }
        // stage B tile BNx32
#pragma unroll
        for (int r = 0; r < BR; r++) {
            int chunk = r * 256 + t;
            async16(Bh + (size_t)(n0 + (chunk >> 2)) * ldb + k0 + ((chunk & 3) << 3),
                    &lB[(r * 256 + w * 64) * 8]);
        }
        __syncthreads();   // drains vmcnt before barrier

        bf16x8 af[4], bfr[NT];
#pragma unroll
        for (int i = 0; i < 4; i++)
            af[i] = *(const bf16x8*)&lA[(wm * 64 + i * 16 + fr) * 32 + fq * 8];
#pragma unroll
        for (int j = 0; j < NT; j++)
            bfr[j] = *(const bf16x8*)&lB[(wn * WN + j * 16 + fr) * 32 + fq * 8];
#pragma unroll
        for (int i = 0; i < 4; i++)
#pragma unroll
            for (int j = 0; j < NT; j++)
                acc[i][j] = __builtin_amdgcn_mfma_f32_16x16x32_bf16(
                    af[i], bfr[j], acc[i][j], 0, 0, 0);
        __syncthreads();
    }

    // epilogue: C/D layout col=lane&15, row=(lane>>4)*4+reg
    const size_t cbase = (size_t)blockIdx.z * cHead;
#pragma unroll
    for (int i = 0; i < 4; i++) {
        int row = m0 + wm * 64 + i * 16 + fq * 4;
#pragma unroll
        for (int j = 0; j < NT; j++) {
            int col = n0 + wn * WN + j * 16 + fr;
#pragma unroll
            for (int r = 0; r < 4; r++) {
                float v = acc[i][j][r] * alpha;
                if (WBIAS) {
                    if (col >= 33) v += wb[(size_t)(col - 33) * H_ + blockIdx.z];
                }
                if (BF16OUT)
                    ((u16*)Cp)[cbase + (size_t)(row + r) * ldc + col] = f2bf(v);
                else
                    ((float*)Cp)[cbase + (size_t)(row + r) * ldc + col] = v;
            }
        }
    }
}

// ---------------------------------------------------------------------------
// biasL[b][k*8+h] = (z @ W_z)[b, k*8+h]
// ---------------------------------------------------------------------------
__global__ __launch_bounds__(256) void biasl_kernel(
    const float* __restrict__ z, const float* __restrict__ Wz,
    float* __restrict__ biasL)
{
    const int t = threadIdx.x;
    if (t < KN * H_) {
        for (int b = 0; b < B_; b++) {
            float s = 0.f;
            for (int l = 0; l < CL; l++) s += z[b * CL + l] * Wz[l * (KN * H_) + t];
            biasL[b * (KN * H_) + t] = s;
        }
    }
}

// ---------------------------------------------------------------------------
// Fused attention: one block per (b,n).
// LDS swizzle on ehs rows: byte ^= ((k&7)<<4) ^ ((k&24)<<2)  (bits 4-6 only,
// bijective involution within each 128B window; row stride 1280B = 10*128B).
//  - logits-phase b128 row reads: legal (16B chunks permuted), ~4-way spread.
//  - Eagg-phase u16 COLUMN reads (fixed c, k varying): conflict-light.
// Phase 0: stage hE[b,n] 30x640 f32 -> bf16 LDS via v_cvt_pk_bf16_f32;
//          threads with row>=30 zero rows 30,31 (read by Eagg MFMA, x0 att).
// Phase 1 (waves 0,1): logits[8x30] = Qt[8x640].E^T via MFMA; Qt A-frags
//          straight from global (bias_edges pre-folded into Qt). +biasL, mask.
// Phase 2: wave-parallel softmax -> att_b bf16 [16][32]; threads 64-127 zero
//          att_b rows 8-15 (A-operand padding rows).
// Phase 3: Eagg = att_b @ E via MFMA: 40 c-tiles of 16x16x32, 10 per wave.
// LDS ~43.1 KB -> 3 blocks/CU by LDS, 4 by waves; ehs = 32 rows (30 data +
// 2 zero) * 640 u16 = 40960 B.
// NOTE: Qt and Eagg alias (in-place); logits-phase Qt reads complete before
// the barrier preceding Eagg stores. No __restrict__ on those params.
// ---------------------------------------------------------------------------
__global__ __launch_bounds__(256) void attn_kernel(
    const float* __restrict__ hE, const float* __restrict__ mask,
    const u16* Qt, const float* __restrict__ biasL, u16* Eagg)
{
    __shared__ __align__(16) u16 ehs[32 * CI];     // 40960 B, swizzled rows
    __shared__ float logit_s[H_ * 32];             // [h][32]  1024 B
    __shared__ __align__(8) u16 att_b[16 * 32];    // bf16 A-operand, 1024 B
    __shared__ float mask_s[KN];                   //           120 B

    const int bn   = blockIdx.x;
    const int b    = bn >> 11;              // N_=2048
    const int t    = threadIdx.x;
    const int w    = t >> 6;
    const int lane = t & 63;
    const int fr   = lane & 15;
    const int fq   = lane >> 4;
    char* ebase = (char*)ehs;

    // ---- Phase 0: stage h_E[b,n] -> LDS bf16 (swizzled); zero rows 30,31 ----
    const float* he = hE + (size_t)bn * KN * CI;
    {
        const int kr = t >> 3;              // row 0..31
        const int c8 = t & 7;               // 8B-chunk phase within row
        char* wrow = ebase + kr * 1280;
        const u32 swz = (u32)(((kr & 7) << 4) ^ ((kr & 24) << 2));
        if (kr < KN) {
            const float* hrow = he + kr * CI + c8 * 4;
#pragma unroll 5
            for (int i = 0; i < 20; i++) {
                float4 v = *(const float4*)(hrow + i * 32);
                uint2 p;
                p.x = pk2bf(v.x, v.y);
                p.y = pk2bf(v.z, v.w);
                *(uint2*)(wrow + (((u32)((c8 + i * 8) * 8)) ^ swz)) = p;
            }
        } else {
            uint2 zz; zz.x = 0u; zz.y = 0u;
#pragma unroll 5
            for (int i = 0; i < 20; i++)
                *(uint2*)(wrow + (((u32)((c8 + i * 8) * 8)) ^ swz)) = zz;
        }
    }
    if (t < KN) mask_s[t] = mask[(size_t)bn * KN + t];
    __syncthreads();

    // ---- Phase 1: logits via MFMA (waves 0,1) ----
    if (w < 2) {
        const int h8 = fr & 7;              // A row = head (rows 8-15 dup)
        const u16* qrow = Qt + (size_t)bn * (H_ * CI) + h8 * CI + fq * 8;
        int nr = w * 16 + fr;               // neighbor row for B fragment
        if (nr > KN - 1) nr = KN - 1;       // clamp pad rows (discarded)
        const char* erow = ebase + nr * 1280;
        const int swz = ((nr & 7) << 4) ^ ((nr & 24) << 2);
        f32x4 lacc = {0.f, 0.f, 0.f, 0.f};
#pragma unroll 4
        for (int kk = 0; kk < CI / 32; kk++) {           // 20 k-steps
            bf16x8 a  = *(const bf16x8*)(qrow + kk * 32);
            bf16x8 bf = *(const bf16x8*)(erow + ((kk * 64 + fq * 16) ^ swz));
            lacc = __builtin_amdgcn_mfma_f32_16x16x32_bf16(a, bf, lacc, 0, 0, 0);
        }
        // C layout: col = fr (neighbor within tile), row = fq*4+r (head 0-7)
        int k = w * 16 + fr;
        if (fq < 2 && k < KN) {
            float mk = mask_s[k];
            const float* blp = &biasL[b * (KN * H_) + k * H_];
#pragma unroll
            for (int r = 0; r < 4; r++) {
                int h = fq * 4 + r;
                float lg = lacc[r] + blp[h];
                logit_s[h * 32 + k] = (mk > 0.f) ? lg : NEG_INF;
            }
        }
    }
    __syncthreads();

    // ---- Phase 2: softmax over k, wave-parallel; emit bf16 att_b[16][32] ----
    if (t < 64) {
        const int h  = t >> 3;
        const int kg = t & 7;
        float lv[4];
#pragma unroll
        for (int i = 0; i < 4; i++) {
            int k = kg * 4 + i;
            float v = logit_s[h * 32 + k];
            lv[i] = (k < KN) ? v : NEG_INF;   // k=30,31 unwritten
        }
        float m = fmaxf(fmaxf(lv[0], lv[1]), fmaxf(lv[2], lv[3]));
        m = fmaxf(m, __shfl_xor(m, 1));
        m = fmaxf(m, __shfl_xor(m, 2));
        m = fmaxf(m, __shfl_xor(m, 4));
        float e[4], s = 0.f;
#pragma unroll
        for (int i = 0; i < 4; i++) { e[i] = __expf(lv[i] - m); s += e[i]; }
        s += __shfl_xor(s, 1);
        s += __shfl_xor(s, 2);
        s += __shfl_xor(s, 4);
        float inv = 1.f / s;
        float av[4];
#pragma unroll
        for (int i = 0; i < 4; i++) {
            int k = kg * 4 + i;
            float mk = (k < KN) ? mask_s[k] : 0.f;   // e[i]=0 for k>=30 anyway
            av[i] = e[i] * inv * mk;
        }
        uint2 p;
        p.x = pk2bf(av[0], av[1]);
        p.y = pk2bf(av[2], av[3]);
        *(uint2*)&att_b[h * 32 + kg * 4] = p;
    } else if (t < 128) {
        // zero A-operand pad rows 8-15 (multiplied into discarded D rows)
        const int u = t - 64;                // 0..63
        uint2 zz; zz.x = 0u; zz.y = 0u;
        *(uint2*)&att_b[(8 + (u >> 3)) * 32 + (u & 7) * 4] = zz;
    }
    __syncthreads();

    // ---- Phase 3: Eagg = att_b @ E via MFMA; wave w owns c-tiles w*10..+9 ----
    {
        f32x4 zero4 = {0.f, 0.f, 0.f, 0.f};
        // A-frag: att_b[fr][fq*8+j] (rows 8-15 zero -> D rows 8-15, unused)
        bf16x8 afrag = *(const bf16x8*)&att_b[fr * 32 + fq * 8];
        const u32 fqk  = (u32)(fq * 10240);   // k-row byte base (fq*8*1280)
        const u32 fqs  = (u32)(fq << 5);      // swizzle contribution (k&24)<<2
        const u32 colb = (u32)(w * 320 + fr * 2);  // c-byte for ct0 = w*10
        u16* outp = Eagg + (size_t)bn * (H_ * CI);
#pragma unroll 2
        for (int i = 0; i < 10; i++) {
            const u32 cb = colb + (u32)(i * 32);
            union { u16 u[8]; bf16x8 v; } bu;
#pragma unroll
            for (int j = 0; j < 8; j++) {
                u32 a = ((fqk + (u32)(j * 1280) + cb) ^ ((u32)(j << 4))) ^ fqs;
                bu.u[j] = *(const u16*)(ebase + a);
            }
            f32x4 d = __builtin_amdgcn_mfma_f32_16x16x32_bf16(
                afrag, bu.v, zero4, 0, 0, 0);
            if (fq < 2) {
                int c = w * 160 + i * 16 + fr;
#pragma unroll
                for (int r = 0; r < 4; r++) {
                    int h = fq * 4 + r;
                    outp[h * CI + c] = f2bf1(d[r]);
                }
            }
        }
    }
}

// ---------------------------------------------------------------------------
extern "C" void kernel_launch(void* const* d_in, const int* in_sizes, int n_in,
                              void* d_out, int out_size, void* d_ws, size_t ws_size,
                              hipStream_t stream)
{
    const float* z    = (const float*)d_in[0];
    const float* hV   = (const float*)d_in[1];
    const float* hE   = (const float*)d_in[2];
    const float* mask = (const float*)d_in[3];
    const float* WQ   = (const float*)d_in[4];
    const float* WK   = (const float*)d_in[5];
    const float* WV   = (const float*)d_in[6];
    const float* WO   = (const float*)d_in[7];
    const float* Wz   = (const float*)d_in[8];
    const float* Wb   = (const float*)d_in[9];
    float* out = (float*)d_out;

    char* w = (char*)d_ws;
    // ws layout (~103 MB):
    //  [0,        8.39 MB)  hV_bf (bf16), reused as Hupd_bf after gemm1
    //  [8.39,    16.78 MB)  Q_bf  (bf16)
    //  [16.78,  100.66 MB)  Qt (bf16) 8192x8x640 — Eagg written IN-PLACE here
    //  [100.66 MB, +2.4 MB) WQt, WK_bf, WVt, WOt (bf16), biasL (f32)
    u16*   hV_bf = (u16*)w;
    u16*   Q_bf  = (u16*)(w + 8388608);
    u16*   Qt    = (u16*)(w + 16777216);
    u16*   WQt   = (u16*)(w + 100663296);
    u16*   WK_bf = (u16*)(w + 101187584);
    u16*   WVt   = (u16*)(w + 101842944);
    u16*   WOt   = (u16*)(w + 102498304);
    float* biasL = (float*)(w + 103022592);
    u16*   Eagg  = Qt;       // in-place
    u16*   Hupd  = hV_bf;    // hV_bf dead after gemm1

    // 0) conversions
    cvt_kernel<<<4096, 256, 0, stream>>>(hV, hV_bf, BN_TOT * CH);
    cvt_kernel<<<320, 256, 0, stream>>>(WK, WK_bf, CI * CH);
    cvt_t_kernel<<<1024, 256, 0, stream>>>(WQ, WQt, CH, CH);      // WQt[n][k]
    cvt_t_kernel<<<1280, 256, 0, stream>>>(WV, WVt, CI, CH);      // WVt[d][c]
    cvt_t_kernel<<<1024, 256, 0, stream>>>(WO, WOt, CH, CH);      // WOt[n][k]
    biasl_kernel<<<1, 256, 0, stream>>>(z, Wz, biasL);

    // 1) Q_bf = hV @ W_Q          (M=8192, N=512, K=512)
    mfma_gemm<128, true, false><<<dim3(4, 64, 1), 256, 0, stream>>>(
        hV_bf, WQt, Q_bf, CH, CH, CH, CH, 0, 0, 0, 1.0f, nullptr);
    // 2) Qt = per-head (Q_h @ W_K_h^T)/8 + Wb-fold   (M=8192, N=640, K=64)
    mfma_gemm<128, true, true><<<dim3(5, 64, H_), 256, 0, stream>>>(
        Q_bf, WK_bf, Qt, 64, CH, CH, H_ * CI, 64, 64, CI, 0.125f, Wb);
    // 3) fused logits/softmax/aggregate (Eagg in-place over Qt)
    attn_kernel<<<dim3(BN_TOT), 256, 0, stream>>>(hE, mask, Qt, biasL, Eagg);
    // 4) Hupd = per-head Eagg_h @ W_V_h      (M=8192, N=64, K=640, z=head)
    mfma_gemm<64, true, false><<<dim3(1, 64, H_), 256, 0, stream>>>(
        Eagg, WVt, Hupd, CI, H_ * CI, CI, CH, CI, 64L * CI, 64, 1.0f, nullptr);
    // 5) out = Hupd @ W_O          (M=8192, N=512, K=512)
    mfma_gemm<128, false, false><<<dim3(4, 64, 1), 256, 0, stream>>>(
        Hupd, WOt, out, CH, CH, CH, CH, 0, 0, 0, 1.0f, nullptr);
}

// Round 6
// 1035.450 us; speedup vs baseline: 1.2471x; 1.0156x over previous
//
#include <hip/hip_runtime.h>

// Problem constants
#define B_      4
#define N_      2048
#define KN      30      // neighbors
#define H_      8       // heads
#define D_      64      // head dim
#define CH      512     // NUM_HIDDEN
#define CI      640     // NUM_IN
#define CL      128     // NUM_LATENT
#define BN_TOT  8192    // B_*N_

typedef unsigned short u16;
typedef unsigned int   u32;

typedef __attribute__((ext_vector_type(8))) short bf16x8;
typedef __attribute__((ext_vector_type(4))) float f32x4;

__device__ __forceinline__ float bf2f(u16 u) {
    return __uint_as_float(((u32)u) << 16);
}
__device__ __forceinline__ u16 f2bf(float f) {   // round-to-nearest-even
    u32 u = __float_as_uint(f);
    return (u16)((u + 0x7FFFu + ((u >> 16) & 1u)) >> 16);
}
// HW packed f32->bf16 (RNE), 1 instr for 2 elements (no builtin on gfx950)
__device__ __forceinline__ u32 pk2bf(float lo, float hi) {
    u32 r;
    asm("v_cvt_pk_bf16_f32 %0, %1, %2" : "=v"(r) : "v"(lo), "v"(hi));
    return r;
}
__device__ __forceinline__ u16 f2bf1(float f) {
    return (u16)pk2bf(f, f);
}

#define NEG_INF (-3.4028234663852886e38f)

// async global->LDS, 16B per lane; LDS dest = wave-uniform base + lane*16
__device__ __forceinline__ void async16(const void* g, void* l) {
    __builtin_amdgcn_global_load_lds(
        (const __attribute__((address_space(1))) unsigned int*)g,
        (__attribute__((address_space(3))) unsigned int*)l, 16, 0, 0);
}

// ---------------------------------------------------------------------------
// f32 -> bf16 elementwise (n % 4 == 0)
// ---------------------------------------------------------------------------
__global__ __launch_bounds__(256) void cvt_kernel(
    const float* __restrict__ in, u16* __restrict__ out, int n)
{
    int i4 = (blockIdx.x * 256 + threadIdx.x) * 4;
    if (i4 < n) {
        float4 v = *(const float4*)&in[i4];
        ushort4 s;
        s.x = f2bf(v.x); s.y = f2bf(v.y); s.z = f2bf(v.z); s.w = f2bf(v.w);
        *(ushort4*)&out[i4] = s;
    }
}

// ---------------------------------------------------------------------------
// f32 (R x C) -> bf16 transposed (C x R): out[j*R + i] = in[i*Cc + j]
// LDS-tiled 32x32 (+1 pad) so both global read and write are coalesced.
// R, Cc multiples of 32. 256 threads = 32x8; each thread does 4 sub-rows.
// ---------------------------------------------------------------------------
__global__ __launch_bounds__(256) void cvt_t_kernel(
    const float* __restrict__ in, u16* __restrict__ out, int R, int Cc)
{
    __shared__ float tile_s[32][33];
    const int tx = threadIdx.x & 31;
    const int ty = threadIdx.x >> 5;          // 0..7
    const int ntj = Cc >> 5;
    const int ti = blockIdx.x / ntj;
    const int tj = blockIdx.x - ti * ntj;
#pragma unroll
    for (int s = 0; s < 4; s++) {
        int i = ti * 32 + ty + s * 8;
        tile_s[ty + s * 8][tx] = in[(size_t)i * Cc + tj * 32 + tx];
    }
    __syncthreads();
#pragma unroll
    for (int s = 0; s < 4; s++) {
        int j = tj * 32 + ty + s * 8;
        out[(size_t)j * R + ti * 32 + tx] = f2bf(tile_s[tx][ty + s * 8]);
    }
}

// ---------------------------------------------------------------------------
// MFMA bf16 GEMM: C[128 x BN] += A[128 x K] * Bt[BN x K]^T  per z-slice.
// (unchanged m97 structure; see earlier rounds)
// ---------------------------------------------------------------------------
template<int BN, bool BF16OUT, bool WBIAS>
__global__ __launch_bounds__(256) void mfma_gemm(
    const u16* __restrict__ A, const u16* __restrict__ Bt, void* __restrict__ Cp,
    int K, int lda, int ldb, int ldc,
    long aHead, long bHead, long cHead, float alpha,
    const float* __restrict__ wb)
{
    constexpr int WN = BN / 2;        // wave n-extent
    constexpr int NT = WN / 16;       // n-tiles per wave
    constexpr int BR = (BN * 4) / 256; // B staging rounds

    __shared__ u16 lA[128 * 32];
    __shared__ u16 lB[BN * 32];

    const int t    = threadIdx.x;
    const int w    = t >> 6;
    const int lane = t & 63;
    const int fr   = lane & 15;       // fragment row (m or n)
    const int fq   = lane >> 4;       // quad (k-chunk / acc row group)
    const int wm   = w >> 1, wn = w & 1;
    const int m0   = blockIdx.y * 128;
    const int n0   = blockIdx.x * BN;

    const u16* Ah = A  + (size_t)blockIdx.z * aHead;
    const u16* Bh = Bt + (size_t)blockIdx.z * bHead;

    f32x4 zero = {0.f, 0.f, 0.f, 0.f};
    f32x4 acc[4][NT];
#pragma unroll
    for (int i = 0; i < 4; i++)
#pragma unroll
        for (int j = 0; j < NT; j++) acc[i][j] = zero;

    for (int k0 = 0; k0 < K; k0 += 32) {
        // stage A tile 128x32 (2 rounds of 256 lanes x 16B)
#pragma unroll
        for (int r = 0; r < 2; r++) {
            int chunk = r * 256 + t;
            async16(Ah + (size_t)(m0 + (chunk >> 2)) * lda + k0 + ((chunk & 3) << 3),
                    &lA[(r * 256 + w * 64) * 8]);
        }
        // stage B tile BNx32
#pragma unroll
        for (int r = 0; r < BR; r++) {
            int chunk = r * 256 + t;
            async16(Bh + (size_t)(n0 + (chunk >> 2)) * ldb + k0 + ((chunk & 3) << 3),
                    &lB[(r * 256 + w * 64) * 8]);
        }
        __syncthreads();   // drains vmcnt before barrier

        bf16x8 af[4], bfr[NT];
#pragma unroll
        for (int i = 0; i < 4; i++)
            af[i] = *(const bf16x8*)&lA[(wm * 64 + i * 16 + fr) * 32 + fq * 8];
#pragma unroll
        for (int j = 0; j < NT; j++)
            bfr[j] = *(const bf16x8*)&lB[(wn * WN + j * 16 + fr) * 32 + fq * 8];
#pragma unroll
        for (int i = 0; i < 4; i++)
#pragma unroll
            for (int j = 0; j < NT; j++)
                acc[i][j] = __builtin_amdgcn_mfma_f32_16x16x32_bf16(
                    af[i], bfr[j], acc[i][j], 0, 0, 0);
        __syncthreads();
    }

    // epilogue: C/D layout col=lane&15, row=(lane>>4)*4+reg
    const size_t cbase = (size_t)blockIdx.z * cHead;
#pragma unroll
    for (int i = 0; i < 4; i++) {
        int row = m0 + wm * 64 + i * 16 + fq * 4;
#pragma unroll
        for (int j = 0; j < NT; j++) {
            int col = n0 + wn * WN + j * 16 + fr;
#pragma unroll
            for (int r = 0; r < 4; r++) {
                float v = acc[i][j][r] * alpha;
                if (WBIAS) {
                    if (col >= 33) v += wb[(size_t)(col - 33) * H_ + blockIdx.z];
                }
                if (BF16OUT)
                    ((u16*)Cp)[cbase + (size_t)(row + r) * ldc + col] = f2bf(v);
                else
                    ((float*)Cp)[cbase + (size_t)(row + r) * ldc + col] = v;
            }
        }
    }
}

// ---------------------------------------------------------------------------
// biasL[b][k*8+h] = (z @ W_z)[b, k*8+h] — one block per b, z staged in LDS.
// ---------------------------------------------------------------------------
__global__ __launch_bounds__(256) void biasl_kernel(
    const float* __restrict__ z, const float* __restrict__ Wz,
    float* __restrict__ biasL)
{
    __shared__ float z_s[CL];
    const int b = blockIdx.x;
    const int t = threadIdx.x;
    if (t < CL) z_s[t] = z[b * CL + t];
    __syncthreads();
    if (t < KN * H_) {
        float s = 0.f;
#pragma unroll 8
        for (int l = 0; l < CL; l++) s += z_s[l] * Wz[l * (KN * H_) + t];
        biasL[b * (KN * H_) + t] = s;
    }
}

// ---------------------------------------------------------------------------
// Fused attention: one block per (b,n).  (EXACT round-4 version — passing)
// LDS swizzle on ehs rows: byte ^= ((k&7)<<4) ^ ((k&24)<<2)  (bits 4-6 only,
// bijective involution within each 128B window; row stride 1280B = 10*128B).
// Phase 0: stage hE[b,n] 30x640 f32 -> bf16 LDS via v_cvt_pk_bf16_f32;
//          threads with row>=30 zero rows 30,31 (read by Eagg MFMA, x0 att).
// Phase 1 (waves 0,1): logits[8x30] = Qt[8x640].E^T via MFMA; Qt A-frags
//          straight from global (bias_edges pre-folded into Qt). +biasL, mask.
// Phase 2: wave-parallel softmax -> att_b bf16 [16][32]; threads 64-127 zero
//          att_b rows 8-15 (A-operand padding rows).
// Phase 3: Eagg = att_b @ E via MFMA: 40 c-tiles of 16x16x32, 10 per wave.
// NOTE: Qt and Eagg alias (in-place); logits-phase Qt reads complete before
// the barrier preceding Eagg stores. No __restrict__ on those params.
// ---------------------------------------------------------------------------
__global__ __launch_bounds__(256) void attn_kernel(
    const float* __restrict__ hE, const float* __restrict__ mask,
    const u16* Qt, const float* __restrict__ biasL, u16* Eagg)
{
    __shared__ __align__(16) u16 ehs[32 * CI];     // 40960 B, swizzled rows
    __shared__ float logit_s[H_ * 32];             // [h][32]  1024 B
    __shared__ __align__(8) u16 att_b[16 * 32];    // bf16 A-operand, 1024 B
    __shared__ float mask_s[KN];                   //           120 B

    const int bn   = blockIdx.x;
    const int b    = bn >> 11;              // N_=2048
    const int t    = threadIdx.x;
    const int w    = t >> 6;
    const int lane = t & 63;
    const int fr   = lane & 15;
    const int fq   = lane >> 4;
    char* ebase = (char*)ehs;

    // ---- Phase 0: stage h_E[b,n] -> LDS bf16 (swizzled); zero rows 30,31 ----
    const float* he = hE + (size_t)bn * KN * CI;
    {
        const int kr = t >> 3;              // row 0..31
        const int c8 = t & 7;               // 8B-chunk phase within row
        char* wrow = ebase + kr * 1280;
        const u32 swz = (u32)(((kr & 7) << 4) ^ ((kr & 24) << 2));
        if (kr < KN) {
            const float* hrow = he + kr * CI + c8 * 4;
#pragma unroll 5
            for (int i = 0; i < 20; i++) {
                float4 v = *(const float4*)(hrow + i * 32);
                uint2 p;
                p.x = pk2bf(v.x, v.y);
                p.y = pk2bf(v.z, v.w);
                *(uint2*)(wrow + (((u32)((c8 + i * 8) * 8)) ^ swz)) = p;
            }
        } else {
            uint2 zz; zz.x = 0u; zz.y = 0u;
#pragma unroll 5
            for (int i = 0; i < 20; i++)
                *(uint2*)(wrow + (((u32)((c8 + i * 8) * 8)) ^ swz)) = zz;
        }
    }
    if (t < KN) mask_s[t] = mask[(size_t)bn * KN + t];
    __syncthreads();

    // ---- Phase 1: logits via MFMA (waves 0,1) ----
    if (w < 2) {
        const int h8 = fr & 7;              // A row = head (rows 8-15 dup)
        const u16* qrow = Qt + (size_t)bn * (H_ * CI) + h8 * CI + fq * 8;
        int nr = w * 16 + fr;               // neighbor row for B fragment
        if (nr > KN - 1) nr = KN - 1;       // clamp pad rows (discarded)
        const char* erow = ebase + nr * 1280;
        const int swz = ((nr & 7) << 4) ^ ((nr & 24) << 2);
        f32x4 lacc = {0.f, 0.f, 0.f, 0.f};
#pragma unroll 4
        for (int kk = 0; kk < CI / 32; kk++) {           // 20 k-steps
            bf16x8 a  = *(const bf16x8*)(qrow + kk * 32);
            bf16x8 bf = *(const bf16x8*)(erow + ((kk * 64 + fq * 16) ^ swz));
            lacc = __builtin_amdgcn_mfma_f32_16x16x32_bf16(a, bf, lacc, 0, 0, 0);
        }
        // C layout: col = fr (neighbor within tile), row = fq*4+r (head 0-7)
        int k = w * 16 + fr;
        if (fq < 2 && k < KN) {
            float mk = mask_s[k];
            const float* blp = &biasL[b * (KN * H_) + k * H_];
#pragma unroll
            for (int r = 0; r < 4; r++) {
                int h = fq * 4 + r;
                float lg = lacc[r] + blp[h];
                logit_s[h * 32 + k] = (mk > 0.f) ? lg : NEG_INF;
            }
        }
    }
    __syncthreads();

    // ---- Phase 2: softmax over k, wave-parallel; emit bf16 att_b[16][32] ----
    if (t < 64) {
        const int h  = t >> 3;
        const int kg = t & 7;
        float lv[4];
#pragma unroll
        for (int i = 0; i < 4; i++) {
            int k = kg * 4 + i;
            float v = logit_s[h * 32 + k];
            lv[i] = (k < KN) ? v : NEG_INF;   // k=30,31 unwritten
        }
        float m = fmaxf(fmaxf(lv[0], lv[1]), fmaxf(lv[2], lv[3]));
        m = fmaxf(m, __shfl_xor(m, 1));
        m = fmaxf(m, __shfl_xor(m, 2));
        m = fmaxf(m, __shfl_xor(m, 4));
        float e[4], s = 0.f;
#pragma unroll
        for (int i = 0; i < 4; i++) { e[i] = __expf(lv[i] - m); s += e[i]; }
        s += __shfl_xor(s, 1);
        s += __shfl_xor(s, 2);
        s += __shfl_xor(s, 4);
        float inv = 1.f / s;
        float av[4];
#pragma unroll
        for (int i = 0; i < 4; i++) {
            int k = kg * 4 + i;
            float mk = (k < KN) ? mask_s[k] : 0.f;   // e[i]=0 for k>=30 anyway
            av[i] = e[i] * inv * mk;
        }
        uint2 p;
        p.x = pk2bf(av[0], av[1]);
        p.y = pk2bf(av[2], av[3]);
        *(uint2*)&att_b[h * 32 + kg * 4] = p;
    } else if (t < 128) {
        // zero A-operand pad rows 8-15 (multiplied into discarded D rows)
        const int u = t - 64;                // 0..63
        uint2 zz; zz.x = 0u; zz.y = 0u;
        *(uint2*)&att_b[(8 + (u >> 3)) * 32 + (u & 7) * 4] = zz;
    }
    __syncthreads();

    // ---- Phase 3: Eagg = att_b @ E via MFMA; wave w owns c-tiles w*10..+9 ----
    {
        f32x4 zero4 = {0.f, 0.f, 0.f, 0.f};
        // A-frag: att_b[fr][fq*8+j] (rows 8-15 zero -> D rows 8-15, unused)
        bf16x8 afrag = *(const bf16x8*)&att_b[fr * 32 + fq * 8];
        const u32 fqk  = (u32)(fq * 10240);   // k-row byte base (fq*8*1280)
        const u32 fqs  = (u32)(fq << 5);      // swizzle contribution (k&24)<<2
        const u32 colb = (u32)(w * 320 + fr * 2);  // c-byte for ct0 = w*10
        u16* outp = Eagg + (size_t)bn * (H_ * CI);
#pragma unroll 2
        for (int i = 0; i < 10; i++) {
            const u32 cb = colb + (u32)(i * 32);
            union { u16 u[8]; bf16x8 v; } bu;
#pragma unroll
            for (int j = 0; j < 8; j++) {
                u32 a = ((fqk + (u32)(j * 1280) + cb) ^ ((u32)(j << 4))) ^ fqs;
                bu.u[j] = *(const u16*)(ebase + a);
            }
            f32x4 d = __builtin_amdgcn_mfma_f32_16x16x32_bf16(
                afrag, bu.v, zero4, 0, 0, 0);
            if (fq < 2) {
                int c = w * 160 + i * 16 + fr;
#pragma unroll
                for (int r = 0; r < 4; r++) {
                    int h = fq * 4 + r;
                    outp[h * CI + c] = f2bf1(d[r]);
                }
            }
        }
    }
}

// ---------------------------------------------------------------------------
extern "C" void kernel_launch(void* const* d_in, const int* in_sizes, int n_in,
                              void* d_out, int out_size, void* d_ws, size_t ws_size,
                              hipStream_t stream)
{
    const float* z    = (const float*)d_in[0];
    const float* hV   = (const float*)d_in[1];
    const float* hE   = (const float*)d_in[2];
    const float* mask = (const float*)d_in[3];
    const float* WQ   = (const float*)d_in[4];
    const float* WK   = (const float*)d_in[5];
    const float* WV   = (const float*)d_in[6];
    const float* WO   = (const float*)d_in[7];
    const float* Wz   = (const float*)d_in[8];
    const float* Wb   = (const float*)d_in[9];
    float* out = (float*)d_out;

    char* w = (char*)d_ws;
    // ws layout (~103 MB):
    //  [0,        8.39 MB)  hV_bf (bf16), reused as Hupd_bf after gemm1
    //  [8.39,    16.78 MB)  Q_bf  (bf16)
    //  [16.78,  100.66 MB)  Qt (bf16) 8192x8x640 — Eagg written IN-PLACE here
    //  [100.66 MB, +2.4 MB) WQt, WK_bf, WVt, WOt (bf16), biasL (f32)
    u16*   hV_bf = (u16*)w;
    u16*   Q_bf  = (u16*)(w + 8388608);
    u16*   Qt    = (u16*)(w + 16777216);
    u16*   WQt   = (u16*)(w + 100663296);
    u16*   WK_bf = (u16*)(w + 101187584);
    u16*   WVt   = (u16*)(w + 101842944);
    u16*   WOt   = (u16*)(w + 102498304);
    float* biasL = (float*)(w + 103022592);
    u16*   Eagg  = Qt;       // in-place
    u16*   Hupd  = hV_bf;    // hV_bf dead after gemm1

    // 0) conversions
    cvt_kernel<<<4096, 256, 0, stream>>>(hV, hV_bf, BN_TOT * CH);
    cvt_kernel<<<320, 256, 0, stream>>>(WK, WK_bf, CI * CH);
    cvt_t_kernel<<<256, 256, 0, stream>>>(WQ, WQt, CH, CH);       // WQt[n][k]
    cvt_t_kernel<<<320, 256, 0, stream>>>(WV, WVt, CI, CH);       // WVt[d][c]
    cvt_t_kernel<<<256, 256, 0, stream>>>(WO, WOt, CH, CH);       // WOt[n][k]
    biasl_kernel<<<4, 256, 0, stream>>>(z, Wz, biasL);

    // 1) Q_bf = hV @ W_Q          (M=8192, N=512, K=512)
    mfma_gemm<128, true, false><<<dim3(4, 64, 1), 256, 0, stream>>>(
        hV_bf, WQt, Q_bf, CH, CH, CH, CH, 0, 0, 0, 1.0f, nullptr);
    // 2) Qt = per-head (Q_h @ W_K_h^T)/8 + Wb-fold   (M=8192, N=640, K=64)
    mfma_gemm<128, true, true><<<dim3(5, 64, H_), 256, 0, stream>>>(
        Q_bf, WK_bf, Qt, 64, CH, CH, H_ * CI, 64, 64, CI, 0.125f, Wb);
    // 3) fused logits/softmax/aggregate (Eagg in-place over Qt)
    attn_kernel<<<dim3(BN_TOT), 256, 0, stream>>>(hE, mask, Qt, biasL, Eagg);
    // 4) Hupd = per-head Eagg_h @ W_V_h      (M=8192, N=64, K=640, z=head)
    mfma_gemm<64, true, false><<<dim3(1, 64, H_), 256, 0, stream>>>(
        Eagg, WVt, Hupd, CI, H_ * CI, CI, CH, CI, 64L * CI, 64, 1.0f, nullptr);
    // 5) out = Hupd @ W_O          (M=8192, N=512, K=512)
    mfma_gemm<128, false, false><<<dim3(4, 64, 1), 256, 0, stream>>>(
        Hupd, WOt, out, CH, CH, CH, CH, 0, 0, 0, 1.0f, nullptr);
}